// Round 7
// baseline (586.367 us; speedup 1.0000x reference)
//
#include <hip/hip_runtime.h>
#include <hip/hip_bf16.h>
#include <hip/hip_cooperative_groups.h>

namespace cg = cooperative_groups;

// N=50000 nodes, F=64, H=2, E=800000.
// qk = x @ W_qk + b -> [N,H,2,F]; s[e,h] = <q[row],k[col]>; sparse softmax per row; mean heads.
// Softmax WITHOUT max subtraction (shift-invariant; |s| <~ 15, safe in fp32).
// Whole pipeline = ONE cooperative kernel with grid.sync() between phases
// (R6 evidence: ~15-20us overhead per separate launch in this harness).
// MFMA 16x16x32 bf16 layouts (HW-verified): A[m=l&15][k=quad*8+j], B[k=quad*8+j][n=l&15],
// D col=l&15 row=quad*4+reg.

#define NFEAT 64
#define NCOL  256   // 2*H*F

typedef __attribute__((ext_vector_type(8))) short bf16x8;
typedef __attribute__((ext_vector_type(4))) float f32x4;

__device__ __forceinline__ unsigned short f2bf(float f) {
    union { __hip_bfloat16 h; unsigned short u; } cv;
    cv.h = __float2bfloat16(f);
    return cv.u;
}

__device__ __forceinline__ float dot_bf16x2(unsigned a, unsigned b) {
    float alo = __uint_as_float(a << 16), ahi = __uint_as_float(a & 0xFFFF0000u);
    float blo = __uint_as_float(b << 16), bhi = __uint_as_float(b & 0xFFFF0000u);
    return alo * blo + ahi * bhi;
}

__global__ __launch_bounds__(256, 4) void fused_all(
    const float* __restrict__ x, const float* __restrict__ W, const float* __restrict__ b,
    const int* __restrict__ ei, float* __restrict__ out,
    unsigned short* __restrict__ q, unsigned short* __restrict__ k,
    float* __restrict__ ex, float* __restrict__ den,
    unsigned short* __restrict__ Wt, int N, int E)
{
    __shared__ unsigned short WtL[NCOL * NFEAT];  // 32 KB
    __shared__ float bL[NCOL];                    // 1 KB
    cg::grid_group grid = cg::this_grid();

    const int tid  = threadIdx.x;
    const int gtid = blockIdx.x * 256 + tid;
    const int gsz  = gridDim.x * 256;

    // ---------- Phase 0: zero denom + build Wt[c][k] bf16 ----------
    for (int t = gtid; t < 2 * N; t += gsz) den[t] = 0.f;
    for (int i = gtid; i < NCOL * NFEAT; i += gsz) {
        const int kk = i >> 8, c = i & 255;          // W[k][c] row-major, coalesced read
        Wt[(size_t)c * 64 + kk] = f2bf(W[i]);
    }
    __threadfence();
    grid.sync();

    // ---------- Phase 1: qk projection via MFMA ----------
    // Block stages WtL+bias once; grid-stride over 128-row chunks (4 waves x 32 rows).
    for (int i = tid; i < NCOL * NFEAT / 2; i += 256)
        ((unsigned*)WtL)[i] = ((const unsigned*)Wt)[i];
    if (tid < NCOL) bL[tid] = b[tid];
    __syncthreads();

    const int lane = tid & 63;
    const int wv   = tid >> 6;
    const int l15  = lane & 15;
    const int quad = lane >> 4;

    for (int chunk = blockIdx.x; chunk * 128 < N; chunk += gridDim.x) {
        const int base = chunk * 128 + wv * 32;
        if (base < N) {
            bf16x8 afrag[2][2];
#pragma unroll
            for (int s = 0; s < 2; ++s) {
                int m = base + s * 16 + l15;
                if (m >= N) m = N - 1;               // clamp; stores guarded
                const float* xp = x + (size_t)m * NFEAT + quad * 8;
#pragma unroll
                for (int ks = 0; ks < 2; ++ks) {
                    float4 a0 = *(const float4*)(xp + ks * 32);
                    float4 a1 = *(const float4*)(xp + ks * 32 + 4);
                    bf16x8 f;
                    f[0] = f2bf(a0.x); f[1] = f2bf(a0.y); f[2] = f2bf(a0.z); f[3] = f2bf(a0.w);
                    f[4] = f2bf(a1.x); f[5] = f2bf(a1.y); f[6] = f2bf(a1.z); f[7] = f2bf(a1.w);
                    afrag[s][ks] = f;
                }
            }
#pragma unroll 4
            for (int ct = 0; ct < 16; ++ct) {
                const int c = ct * 16 + l15;
                bf16x8 b0 = *(const bf16x8*)(WtL + (size_t)c * 64 + quad * 8);
                bf16x8 b1 = *(const bf16x8*)(WtL + (size_t)c * 64 + 32 + quad * 8);
                const float bias = bL[c];
                const int h   = c >> 7;
                const int isk = (c >> 6) & 1;
                const int f0  = c & 63;
                unsigned short* dst = isk ? k : q;
#pragma unroll
                for (int s = 0; s < 2; ++s) {
                    f32x4 acc = {0.f, 0.f, 0.f, 0.f};
                    acc = __builtin_amdgcn_mfma_f32_16x16x32_bf16(afrag[s][0], b0, acc, 0, 0, 0);
                    acc = __builtin_amdgcn_mfma_f32_16x16x32_bf16(afrag[s][1], b1, acc, 0, 0, 0);
#pragma unroll
                    for (int r = 0; r < 4; ++r) {
                        const int m = base + s * 16 + quad * 4 + r;
                        if (m < N)
                            dst[(size_t)m * 128 + h * 64 + f0] = f2bf(acc[r] + bias);
                    }
                }
            }
        }
    }
    __threadfence();
    grid.sync();

    // ---------- Phase 2: scores -> exp -> segment-sum (4 edges / 16-lane group) ----------
    {
        const int lane16  = tid & 15;
        const int gstride = gsz >> 4;
        for (int grp = gtid >> 4; grp * 4 < E; grp += gstride) {
            const int g0 = grp * 4;
            int v = 0;
            if (lane16 < 4)      v = ei[g0 + lane16];
            else if (lane16 < 8) v = ei[E + g0 + (lane16 - 4)];
            int rows[4], cols[4];
#pragma unroll
            for (int i = 0; i < 4; ++i) {
                rows[i] = __shfl(v, i, 16);
                cols[i] = __shfl(v, 4 + i, 16);
            }
            uint4 qa[4], ka[4];
#pragma unroll
            for (int i = 0; i < 4; ++i) {
                qa[i] = ((const uint4*)(q + (size_t)rows[i] * 128))[lane16];
                ka[i] = ((const uint4*)(k + (size_t)cols[i] * 128))[lane16];
            }
#pragma unroll
            for (int i = 0; i < 4; ++i) {
                float p = dot_bf16x2(qa[i].x, ka[i].x) + dot_bf16x2(qa[i].y, ka[i].y)
                        + dot_bf16x2(qa[i].z, ka[i].z) + dot_bf16x2(qa[i].w, ka[i].w);
                p += __shfl_xor(p, 1);
                p += __shfl_xor(p, 2);
                p += __shfl_xor(p, 4);
                if ((lane16 & 7) == 0 && g0 + i < E) {
                    const int h = lane16 >> 3;
                    const float e = __expf(p);
                    ex[(size_t)(g0 + i) * 2 + h] = e;
                    atomicAdd(&den[(size_t)rows[i] * 2 + h], e);
                }
            }
        }
    }
    __threadfence();
    grid.sync();

    // ---------- Phase 3: normalize + mean over heads ----------
    for (int e = gtid; e < E; e += gsz) {
        const int row = ei[e];
        const float2 exv = *(const float2*)&ex[(size_t)e * 2];
        const float2 dv  = *(const float2*)&den[(size_t)row * 2];
        out[e] = 0.5f * (exv.x / dv.x + exv.y / dv.y);
    }
}

extern "C" void kernel_launch(void* const* d_in, const int* in_sizes, int n_in,
                              void* d_out, int out_size, void* d_ws, size_t ws_size,
                              hipStream_t stream)
{
    const float* x   = (const float*)d_in[0];
    const float* W   = (const float*)d_in[1];
    const float* b   = (const float*)d_in[2];
    const int*   ei  = (const int*)d_in[3];
    float*       out = (float*)d_out;

    int N = in_sizes[0] / NFEAT;     // 50000
    int E = in_sizes[3] / 2;         // 800000

    char* ws = (char*)d_ws;
    size_t off = 0;
    auto alloc = [&](size_t bytes) { void* p = ws + off; off += (bytes + 255) & ~(size_t)255; return p; };
    unsigned short* q_ws   = (unsigned short*)alloc((size_t)N * 128 * 2);        // 12.8 MB
    unsigned short* k_ws   = (unsigned short*)alloc((size_t)N * 128 * 2);        // 12.8 MB
    float*          ex_ws  = (float*)alloc((size_t)E * 2 * sizeof(float));       // 6.4 MB
    float*          den_ws = (float*)alloc((size_t)N * 2 * sizeof(float));       // 0.4 MB
    unsigned short* wt_ws  = (unsigned short*)alloc((size_t)NCOL * NFEAT * 2);   // 32 KB
    (void)ws_size;

    // grid: as many co-resident blocks as occupancy allows, capped at 4/CU (LDS 33KB -> 4/CU)
    int perCU = 0;
    hipOccupancyMaxActiveBlocksPerMultiprocessor(&perCU, fused_all, 256, 0);
    if (perCU < 1) perCU = 1;
    if (perCU > 4) perCU = 4;
    int nBlocks = perCU * 256;
    if (nBlocks > 1024) nBlocks = 1024;

    void* args[] = { (void*)&x, (void*)&W, (void*)&b, (void*)&ei, (void*)&out,
                     (void*)&q_ws, (void*)&k_ws, (void*)&ex_ws, (void*)&den_ws,
                     (void*)&wt_ws, (void*)&N, (void*)&E };
    hipLaunchCooperativeKernel(fused_all, dim3(nBlocks), dim3(256), args, 0, stream);
}

// Round 8
// 142.204 us; speedup vs baseline: 4.1234x; 4.1234x over previous
//
#include <hip/hip_runtime.h>
#include <hip/hip_bf16.h>

// N=50000 nodes, F=64, H=2, E=800000.
// qk = x @ W_qk + b -> [N,H,2,F]; s[e,h] = <q[row],k[col]>; sparse softmax per row; mean heads.
// Softmax WITHOUT max subtraction (shift-invariant; |s| <~ 15, safe in fp32).
// 3 kernels: [gemm(+W-transpose+den-zero)] -> [scores+exp+segsum] -> [normalize].
// R7 lesson: NO grid.sync on MI355X (cg barrier cost ~190us/sync at 1024 blocks).
// MFMA 16x16x32 bf16 layouts (HW-verified): A[m=l&15][k=quad*8+j], B[k=quad*8+j][n=l&15],
// D col=l&15 row=quad*4+reg.

#define NFEAT 64
#define NCOL  256   // 2*H*F
#define WT_STRIDE 72  // shorts; 144B row stride: 16B-aligned, bank-shift 4 (2-way reads)

typedef __attribute__((ext_vector_type(8))) short bf16x8;
typedef __attribute__((ext_vector_type(4))) float f32x4;

__device__ __forceinline__ unsigned short f2bf(float f) {
    union { __hip_bfloat16 h; unsigned short u; } cv;
    cv.h = __float2bfloat16(f);
    return cv.u;
}

__device__ __forceinline__ float dot_bf16x2(unsigned a, unsigned b) {
    float alo = __uint_as_float(a << 16), ahi = __uint_as_float(a & 0xFFFF0000u);
    float blo = __uint_as_float(b << 16), bhi = __uint_as_float(b & 0xFFFF0000u);
    return alo * blo + ahi * bhi;
}

// ---------------- Kernel 1: qk projection via MFMA (W transpose folded in) ----------------
// Block: 256 thr = 4 waves; each wave 32 rows (2 stripes x 16) x 256 cols.
// W[k][c] fp32 read coalesced, converted + transposed into LDS WtL[c][k] bf16 (stride 72).
// Zero-inits den. Output bf16 layout: q[n*128 + h*64 + f].
__global__ __launch_bounds__(256) void gemm_qk_mfma(
    const float* __restrict__ x, const float* __restrict__ W,
    const float* __restrict__ b,
    unsigned short* __restrict__ qo, unsigned short* __restrict__ ko,
    float* __restrict__ den, int N)
{
    __shared__ unsigned short WtL[NCOL * WT_STRIDE];  // 36.9 KB
    __shared__ float bL[NCOL];                        // 1 KB
    const int tid = threadIdx.x;

    // stage + transpose: W[k][c] (coalesced read) -> WtL[c*72 + k]
    for (int i = tid; i < NFEAT * NCOL; i += 256) {
        const int kk = i >> 8, c = i & 255;
        WtL[c * WT_STRIDE + kk] = f2bf(W[i]);
    }
    bL[tid] = b[tid];

    // zero denom: 391 blocks * 256 = 100096 >= 2N
    const int t = blockIdx.x * 256 + tid;
    if (t < 2 * N) den[t] = 0.f;

    const int lane = tid & 63;
    const int wv   = tid >> 6;
    const int l15  = lane & 15;
    const int quad = lane >> 4;
    const int base = blockIdx.x * 128 + wv * 32;
    __syncthreads();

    if (base >= N) return;

    // A-frags: [stripe][ks], fp32 x -> bf16
    bf16x8 afrag[2][2];
#pragma unroll
    for (int s = 0; s < 2; ++s) {
        int m = base + s * 16 + l15;
        if (m >= N) m = N - 1;                      // clamp (stores guarded)
        const float* xp = x + (size_t)m * NFEAT + quad * 8;
#pragma unroll
        for (int ks = 0; ks < 2; ++ks) {
            float4 a0 = *(const float4*)(xp + ks * 32);
            float4 a1 = *(const float4*)(xp + ks * 32 + 4);
            bf16x8 f;
            f[0] = f2bf(a0.x); f[1] = f2bf(a0.y); f[2] = f2bf(a0.z); f[3] = f2bf(a0.w);
            f[4] = f2bf(a1.x); f[5] = f2bf(a1.y); f[6] = f2bf(a1.z); f[7] = f2bf(a1.w);
            afrag[s][ks] = f;
        }
    }

#pragma unroll 4
    for (int ct = 0; ct < 16; ++ct) {
        const int c = ct * 16 + l15;
        bf16x8 b0 = *(const bf16x8*)(WtL + (size_t)c * WT_STRIDE + quad * 8);
        bf16x8 b1 = *(const bf16x8*)(WtL + (size_t)c * WT_STRIDE + 32 + quad * 8);
        const float bias = bL[c];
        const int h   = c >> 7;
        const int isk = (c >> 6) & 1;
        const int f0  = c & 63;
        unsigned short* dst = isk ? ko : qo;
#pragma unroll
        for (int s = 0; s < 2; ++s) {
            f32x4 acc = {0.f, 0.f, 0.f, 0.f};
            acc = __builtin_amdgcn_mfma_f32_16x16x32_bf16(afrag[s][0], b0, acc, 0, 0, 0);
            acc = __builtin_amdgcn_mfma_f32_16x16x32_bf16(afrag[s][1], b1, acc, 0, 0, 0);
#pragma unroll
            for (int r = 0; r < 4; ++r) {
                const int m = base + s * 16 + quad * 4 + r;
                if (m < N)
                    dst[(size_t)m * 128 + h * 64 + f0] = f2bf(acc[r] + bias);
            }
        }
    }
}

// ---------------- Kernel 2: scores -> exp -> segment-sum, 4 edges per 16-lane group ----------------
__global__ __launch_bounds__(256) void edge_scores_exp(
    const unsigned short* __restrict__ q, const unsigned short* __restrict__ k,
    const int* __restrict__ ei, float* __restrict__ ex_out,
    float* __restrict__ denom, int E)
{
    const int grp  = (int)((blockIdx.x * 256 + threadIdx.x) >> 4);
    const int lane = threadIdx.x & 15;
    const int g0   = grp * 4;
    if (g0 >= E) return;

    int v = 0;
    if (lane < 4)      v = ei[g0 + lane];
    else if (lane < 8) v = ei[E + g0 + (lane - 4)];
    int rows[4], cols[4];
#pragma unroll
    for (int i = 0; i < 4; ++i) {
        rows[i] = __shfl(v, i, 16);
        cols[i] = __shfl(v, 4 + i, 16);
    }

    uint4 qa[4], ka[4];
#pragma unroll
    for (int i = 0; i < 4; ++i) {
        qa[i] = ((const uint4*)(q + (size_t)rows[i] * 128))[lane];
        ka[i] = ((const uint4*)(k + (size_t)cols[i] * 128))[lane];
    }

#pragma unroll
    for (int i = 0; i < 4; ++i) {
        float p = dot_bf16x2(qa[i].x, ka[i].x) + dot_bf16x2(qa[i].y, ka[i].y)
                + dot_bf16x2(qa[i].z, ka[i].z) + dot_bf16x2(qa[i].w, ka[i].w);
        p += __shfl_xor(p, 1);
        p += __shfl_xor(p, 2);
        p += __shfl_xor(p, 4);
        if ((lane & 7) == 0 && g0 + i < E) {
            const int h  = lane >> 3;
            const float e = __expf(p);
            ex_out[(size_t)(g0 + i) * 2 + h] = e;
            atomicAdd(&denom[(size_t)rows[i] * 2 + h], e);
        }
    }
}

// ---------------- Kernel 3: normalize + mean over heads ----------------
__global__ __launch_bounds__(256) void edge_out_k(
    const int* __restrict__ ei, const float* __restrict__ ex,
    const float* __restrict__ denom, float* __restrict__ out, int E)
{
    const int e = blockIdx.x * 256 + threadIdx.x;
    if (e >= E) return;
    const int row = ei[e];
    const float2 exv = *(const float2*)&ex[(size_t)e * 2];
    const float2 dv  = *(const float2*)&denom[(size_t)row * 2];
    out[e] = 0.5f * (exv.x / dv.x + exv.y / dv.y);
}

extern "C" void kernel_launch(void* const* d_in, const int* in_sizes, int n_in,
                              void* d_out, int out_size, void* d_ws, size_t ws_size,
                              hipStream_t stream)
{
    const float* x   = (const float*)d_in[0];
    const float* W   = (const float*)d_in[1];
    const float* b   = (const float*)d_in[2];
    const int*   ei  = (const int*)d_in[3];
    float*       out = (float*)d_out;

    const int N = in_sizes[0] / NFEAT;     // 50000
    const int E = in_sizes[3] / 2;         // 800000

    char* ws = (char*)d_ws;
    size_t off = 0;
    auto alloc = [&](size_t bytes) { void* p = ws + off; off += (bytes + 255) & ~(size_t)255; return p; };
    unsigned short* q_ws  = (unsigned short*)alloc((size_t)N * 128 * 2);        // 12.8 MB
    unsigned short* k_ws  = (unsigned short*)alloc((size_t)N * 128 * 2);        // 12.8 MB
    float*          ex_ws = (float*)alloc((size_t)E * 2 * sizeof(float));       // 6.4 MB
    float*          den_ws= (float*)alloc((size_t)N * 2 * sizeof(float));       // 0.4 MB
    (void)ws_size;

    gemm_qk_mfma<<<(N + 127) / 128, 256, 0, stream>>>(x, W, b, q_ws, k_ws, den_ws, N);
    edge_scores_exp<<<((size_t)(E + 3) / 4 * 16 + 255) / 256, 256, 0, stream>>>(q_ws, k_ws, ei, ex_ws, den_ws, E);
    edge_out_k<<<(E + 255) / 256, 256, 0, stream>>>(ei, ex_ws, den_ws, out, E);
}